// Round 1
// baseline (260.155 us; speedup 1.0000x reference)
//
#include <hip/hip_runtime.h>
#include <hip/hip_bf16.h>

// Problem constants: B=8, NUM=4 -> BB=32 batches; LQ=128, LP=512, H=512.
#define BBATCH 32
#define LQ 128
#define LP 512
#define HDIM 512
#define GDIM 2560   // 5*H concat width
#define NEG_MAX (-3.402823466e38f)

// ---------------- bias kernel: ep[b,p] = Ep . w_p ; eq[b,q] = Eq . w_q ----------------
__global__ __launch_bounds__(256) void bias_kernel(
    const float* __restrict__ Ep, const float* __restrict__ Eq,
    const float* __restrict__ w, float* __restrict__ ep, float* __restrict__ eq) {
  int wid = blockIdx.x * 4 + (threadIdx.x >> 6);
  int lane = threadIdx.x & 63;
  const float* src; const float* wv; float* dst;
  if (wid < BBATCH * LP) {
    src = Ep + (long)wid * HDIM; wv = w + HDIM; dst = ep + wid;      // w_p = w[H:2H]
  } else {
    int r = wid - BBATCH * LP;
    src = Eq + (long)r * HDIM; wv = w; dst = eq + r;                  // w_q = w[0:H]
  }
  float dot = 0.f;
#pragma unroll
  for (int j = 0; j < 2; j++) {
    int h = 4 * (lane + 64 * j);
    float4 e = *(const float4*)(src + h);
    float4 ww = *(const float4*)(wv + h);
    dot += e.x * ww.x + e.y * ww.y + e.z * ww.z + e.w * ww.w;
  }
#pragma unroll
  for (int off = 32; off; off >>= 1) dot += __shfl_xor(dot, off);
  if (lane == 0) *dst = dot;
}

// ---------------- generic tiled f32 GEMM ----------------
// C[m,n] = sum_k Aelem(m,k) * Belem(k,n)
//   AT=0: A[m*lda+k]   AT=1: A[k*lda+m]
//   BT=0: B[k*ldb+n]   BT=1: B[n*ldb+k]
// UEPI: A scaled by wm[k] on load; epilogue adds biasM[m]+biasN[n], applies mask -> NEG_MAX.
template <bool AT, bool BT, bool UEPI>
__global__ __launch_bounds__(256) void gemm_f32(
    const float* __restrict__ Abase, const float* __restrict__ Bbase,
    float* __restrict__ Cbase, int M, int N, int K, int lda, int ldb, int ldc,
    long sA, long sB, long sC, const float* __restrict__ wm,
    const float* __restrict__ biasM, const float* __restrict__ biasN,
    const int* __restrict__ maskM, const int* __restrict__ maskN) {
  const int bb = blockIdx.z;
  const float* A = Abase + (long)bb * sA;
  const float* Bm = Bbase + (long)bb * sB;
  float* C = Cbase + (long)bb * sC;
  const int m0 = blockIdx.y * 64, n0 = blockIdx.x * 64;
  __shared__ __align__(16) float As[16][68];
  __shared__ __align__(16) float Bs[16][68];
  const int t = threadIdx.x;
  const int tx = t & 15, ty = t >> 4;
  float acc[4][4] = {};
  for (int k0 = 0; k0 < K; k0 += 16) {
    if (!AT) {
      int kq = t & 3, m = t >> 2;
      float4 av = *(const float4*)(A + (long)(m0 + m) * lda + k0 + kq * 4);
      if (UEPI) {
        av.x *= wm[k0 + kq * 4 + 0]; av.y *= wm[k0 + kq * 4 + 1];
        av.z *= wm[k0 + kq * 4 + 2]; av.w *= wm[k0 + kq * 4 + 3];
      }
      As[kq * 4 + 0][m] = av.x; As[kq * 4 + 1][m] = av.y;
      As[kq * 4 + 2][m] = av.z; As[kq * 4 + 3][m] = av.w;
    } else {
      int m = t & 63, kb = t >> 6;
#pragma unroll
      for (int i = 0; i < 4; i++) {
        int k = kb * 4 + i;
        As[k][m] = A[(long)(k0 + k) * lda + m0 + m];
      }
    }
    if (!BT) {
      int n = t & 63, kb = t >> 6;
#pragma unroll
      for (int i = 0; i < 4; i++) {
        int k = kb * 4 + i;
        Bs[k][n] = Bm[(long)(k0 + k) * ldb + n0 + n];
      }
    } else {
      int kq = t & 3, n = t >> 2;
      float4 bv = *(const float4*)(Bm + (long)(n0 + n) * ldb + k0 + kq * 4);
      Bs[kq * 4 + 0][n] = bv.x; Bs[kq * 4 + 1][n] = bv.y;
      Bs[kq * 4 + 2][n] = bv.z; Bs[kq * 4 + 3][n] = bv.w;
    }
    __syncthreads();
#pragma unroll
    for (int kk = 0; kk < 16; kk++) {
      float4 a4 = *(const float4*)&As[kk][ty * 4];
      float4 b4 = *(const float4*)&Bs[kk][tx * 4];
      float a[4] = {a4.x, a4.y, a4.z, a4.w};
      float b[4] = {b4.x, b4.y, b4.z, b4.w};
#pragma unroll
      for (int i = 0; i < 4; i++)
#pragma unroll
        for (int j = 0; j < 4; j++) acc[i][j] += a[i] * b[j];
    }
    __syncthreads();
  }
  if (UEPI) {
    const float* bM = biasM + (long)bb * M;
    const float* bN = biasN + (long)bb * N;
    const int* mM = maskM + (long)bb * M;
    const int* mN = maskN + (long)bb * N;
#pragma unroll
    for (int i = 0; i < 4; i++) {
      int row = m0 + ty * 4 + i;
      float bm = bM[row];
      int mm = mM[row];
      float4 o;
      float* po = &o.x;
#pragma unroll
      for (int j = 0; j < 4; j++) {
        int col = n0 + tx * 4 + j;
        float v = acc[i][j] + bm + bN[col];
        po[j] = (mm && mN[col]) ? v : NEG_MAX;
      }
      *(float4*)(C + (long)row * ldc + n0 + tx * 4) = o;
    }
  } else {
#pragma unroll
    for (int i = 0; i < 4; i++) {
      int row = m0 + ty * 4 + i;
      float4 o = make_float4(acc[i][0], acc[i][1], acc[i][2], acc[i][3]);
      *(float4*)(C + (long)row * ldc + n0 + tx * 4) = o;
    }
  }
}

// ---------------- column softmax over p (axis=1): B_p ----------------
// grid: (4 q-groups of 32, BB). block 256 = 32 q x 8 p-chains.
__global__ __launch_bounds__(256) void colsoftmax_kernel(
    const float* __restrict__ Um, float* __restrict__ Bp,
    const int* __restrict__ mp, const int* __restrict__ mq) {
  int b = blockIdx.y;
  int q0 = blockIdx.x * 32;
  int t = threadIdx.x;
  int qq = t & 31, pp = t >> 5;
  const float* U = Um + (long)b * LP * LQ + q0;
  float m = NEG_MAX, s = 0.f;
  for (int it = 0; it < LP / 8; ++it) {
    int p = it * 8 + pp;
    float v = U[(long)p * LQ + qq];
    float mn = fmaxf(m, v);
    s = s * __expf(m - mn) + __expf(v - mn);
    m = mn;
  }
  __shared__ float rm[8][32], rs[8][32], fm[32], fs[32];
  rm[pp][qq] = m; rs[pp][qq] = s;
  __syncthreads();
  if (pp == 0) {
    float M = rm[0][qq], S = rs[0][qq];
#pragma unroll
    for (int j = 1; j < 8; j++) {
      float mj = rm[j][qq];
      float mn = fmaxf(M, mj);
      S = S * __expf(M - mn) + rs[j][qq] * __expf(mj - mn);
      M = mn;
    }
    fm[qq] = M; fs[qq] = S;
  }
  __syncthreads();
  float M = fm[qq];
  float inv = fs[qq] > 0.f ? 1.f / fs[qq] : 0.f;
  int mqv = mq[b * LQ + q0 + qq];
  for (int it = 0; it < LP / 8; ++it) {
    int p = it * 8 + pp;
    float v = U[(long)p * LQ + qq];
    bool ok = mqv && mp[b * LP + p];
    Bp[(long)b * LP * LQ + (long)p * LQ + q0 + qq] = ok ? __expf(v - M) * inv : 0.f;
  }
}

// ---------------- row softmax over q (axis=2): A_p, in place over Um ----------------
__global__ __launch_bounds__(256) void rowsoftmax_kernel(
    float* __restrict__ Um, const int* __restrict__ mp, const int* __restrict__ mq) {
  int wid = blockIdx.x * 4 + (threadIdx.x >> 6);  // = b*LP + p
  int lane = threadIdx.x & 63;
  int b = wid >> 9;
  float* row = Um + (long)wid * LQ;
  float v0 = row[lane], v1 = row[lane + 64];
  float m = fmaxf(v0, v1);
#pragma unroll
  for (int off = 32; off; off >>= 1) m = fmaxf(m, __shfl_xor(m, off));
  float s = __expf(v0 - m) + __expf(v1 - m);
#pragma unroll
  for (int off = 32; off; off >>= 1) s += __shfl_xor(s, off);
  float inv = s > 0.f ? 1.f / s : 0.f;
  int mpv = mp[wid];
  bool ok0 = mpv && mq[b * LQ + lane];
  bool ok1 = mpv && mq[b * LQ + lane + 64];
  row[lane] = ok0 ? __expf(v0 - m) * inv : 0.f;
  row[lane + 64] = ok1 ? __expf(v1 - m) * inv : 0.f;
}

// ---------------- elementwise epilogue: fill E, E*X1, E*X2 chunks (+mask) ----------------
__global__ __launch_bounds__(128) void epilogue_kernel(
    const float* __restrict__ Ep, const float* __restrict__ Eq,
    const int* __restrict__ mp, const int* __restrict__ mq,
    float* __restrict__ out_gpq, float* __restrict__ out_gqp) {
  int r = blockIdx.x;
  int i = threadIdx.x * 4;
  const float* e;
  float* o;
  float sc;
  if (r < BBATCH * LP) {
    e = Ep + (long)r * HDIM;
    o = out_gqp + (long)r * GDIM;
    sc = (float)mp[r];
  } else {
    int rr = r - BBATCH * LP;
    e = Eq + (long)rr * HDIM;
    o = out_gpq + (long)rr * GDIM;
    sc = (float)mq[rr];
  }
  float4 ev = *(const float4*)(e + i);
  float4 x1 = *(const float4*)(o + HDIM + i);
  float4 x2 = *(const float4*)(o + 2 * HDIM + i);
  float4 oe = make_float4(ev.x * sc, ev.y * sc, ev.z * sc, ev.w * sc);
  float4 p1 = make_float4(ev.x * x1.x * sc, ev.y * x1.y * sc, ev.z * x1.z * sc, ev.w * x1.w * sc);
  float4 p2 = make_float4(ev.x * x2.x * sc, ev.y * x2.y * sc, ev.z * x2.z * sc, ev.w * x2.w * sc);
  *(float4*)(o + i) = oe;
  *(float4*)(o + 3 * HDIM + i) = p1;
  *(float4*)(o + 4 * HDIM + i) = p2;
  if (sc != 1.0f) {
    float4 s1 = make_float4(x1.x * sc, x1.y * sc, x1.z * sc, x1.w * sc);
    float4 s2 = make_float4(x2.x * sc, x2.y * sc, x2.z * sc, x2.w * sc);
    *(float4*)(o + HDIM + i) = s1;
    *(float4*)(o + 2 * HDIM + i) = s2;
  }
}

extern "C" void kernel_launch(void* const* d_in, const int* in_sizes, int n_in,
                              void* d_out, int out_size, void* d_ws, size_t ws_size,
                              hipStream_t stream) {
  const float* Eq = (const float*)d_in[0];   // (32,128,512)
  const float* Ep = (const float*)d_in[1];   // (32,512,512)
  const int* mq = (const int*)d_in[2];       // (32,128)
  const int* mp = (const int*)d_in[3];       // (32,512)
  const float* w = (const float*)d_in[4];    // (1536,)
  float* out = (float*)d_out;
  float* out_gpq = out;                                  // (32,128,2560)
  float* out_gqp = out + (long)BBATCH * LQ * GDIM;       // (32,512,2560)

  float* ws = (float*)d_ws;
  float* ep = ws;                   // 32*512
  float* eqv = ws + 16384;          // 32*128
  float* Um = ws + 20480;           // 32*512*128 (becomes A_p in place)
  float* Bp = Um + (long)BBATCH * LP * LQ;  // 32*512*128

  // 1. bias vectors
  bias_kernel<<<(BBATCH * LP + BBATCH * LQ) / 4, 256, 0, stream>>>(Ep, Eq, w, ep, eqv);

  // 2. U = (Ep .* w_m) @ Eq^T + ep + eq, masked -> Um   (M=512, N=128, K=512; NT)
  gemm_f32<false, true, true><<<dim3(2, 8, BBATCH), 256, 0, stream>>>(
      Ep, Eq, Um, LP, LQ, HDIM, HDIM, HDIM, LQ,
      (long)LP * HDIM, (long)LQ * HDIM, (long)LP * LQ,
      w + 2 * HDIM, ep, eqv, mp, mq);

  // 3. column softmax (over p) -> Bp
  colsoftmax_kernel<<<dim3(4, BBATCH), 256, 0, stream>>>(Um, Bp, mp, mq);

  // 4. row softmax (over q) in-place -> A_p (in Um)
  rowsoftmax_kernel<<<(BBATCH * LP) / 4, 256, 0, stream>>>(Um, mp, mq);

  // 5. A1 = A_p @ Eq  (M=512,N=512,K=128; NN) -> out_gqp chunk1
  gemm_f32<false, false, false><<<dim3(8, 8, BBATCH), 256, 0, stream>>>(
      Um, Eq, out_gqp + HDIM, LP, HDIM, LQ, LQ, HDIM, GDIM,
      (long)LP * LQ, (long)LQ * HDIM, (long)LP * GDIM,
      nullptr, nullptr, nullptr, nullptr, nullptr);

  // 6. B1 = B_p^T @ Ep (M=128,N=512,K=512; TN) -> out_gpq chunk1
  gemm_f32<true, false, false><<<dim3(8, 2, BBATCH), 256, 0, stream>>>(
      Bp, Ep, out_gpq + HDIM, LQ, HDIM, LP, LQ, HDIM, GDIM,
      (long)LP * LQ, (long)LP * HDIM, (long)LQ * GDIM,
      nullptr, nullptr, nullptr, nullptr, nullptr);

  // 7. A2 = A_p @ B1 (M=512,N=512,K=128; NN, B from out) -> out_gqp chunk2
  gemm_f32<false, false, false><<<dim3(8, 8, BBATCH), 256, 0, stream>>>(
      Um, out_gpq + HDIM, out_gqp + 2 * HDIM, LP, HDIM, LQ, LQ, GDIM, GDIM,
      (long)LP * LQ, (long)LQ * GDIM, (long)LP * GDIM,
      nullptr, nullptr, nullptr, nullptr, nullptr);

  // 8. B2 = B_p^T @ A1 (M=128,N=512,K=512; TN, B from out) -> out_gpq chunk2
  gemm_f32<true, false, false><<<dim3(8, 2, BBATCH), 256, 0, stream>>>(
      Bp, out_gqp + HDIM, out_gpq + 2 * HDIM, LQ, HDIM, LP, LQ, GDIM, GDIM,
      (long)LP * LQ, (long)LP * GDIM, (long)LQ * GDIM,
      nullptr, nullptr, nullptr, nullptr, nullptr);

  // 9. elementwise: E chunk, E*X1, E*X2 (+mask rescale of X1,X2 if masked)
  epilogue_kernel<<<BBATCH * LP + BBATCH * LQ, 128, 0, stream>>>(
      Ep, Eq, mp, mq, out_gpq, out_gqp);
}

// Round 2
// 142.570 us; speedup vs baseline: 1.8248x; 1.8248x over previous
//
#include <hip/hip_runtime.h>
#include <hip/hip_bf16.h>

// Problem constants: B=8, NUM=4 -> BB=32 batches; LQ=128, LP=512, H=512.
#define BBATCH 32
#define LQ 128
#define LP 512
#define HDIM 512
#define GDIM 2560   // 5*H concat width
#define NEG_MAX (-3.402823466e38f)

typedef __attribute__((ext_vector_type(8))) short short8;
typedef __attribute__((ext_vector_type(4))) float f32x4;
typedef __attribute__((ext_vector_type(4))) unsigned short ushort4v;

__device__ inline unsigned short f2bf(float f) {
  union { float f; unsigned int u; } v; v.f = f;
  unsigned int r = v.u + 0x7FFFu + ((v.u >> 16) & 1u);  // RNE
  return (unsigned short)(r >> 16);
}

// ---------------- bias kernel: ep[b,p] = Ep . w_p ; eq[b,q] = Eq . w_q ----------------
__global__ __launch_bounds__(256) void bias_kernel(
    const float* __restrict__ Ep, const float* __restrict__ Eq,
    const float* __restrict__ w, float* __restrict__ ep, float* __restrict__ eq) {
  int wid = blockIdx.x * 4 + (threadIdx.x >> 6);
  int lane = threadIdx.x & 63;
  const float* src; const float* wv; float* dst;
  if (wid < BBATCH * LP) {
    src = Ep + (long)wid * HDIM; wv = w + HDIM; dst = ep + wid;      // w_p
  } else {
    int r = wid - BBATCH * LP;
    src = Eq + (long)r * HDIM; wv = w; dst = eq + r;                  // w_q
  }
  float dot = 0.f;
#pragma unroll
  for (int j = 0; j < 2; j++) {
    int h = 4 * (lane + 64 * j);
    float4 e = *(const float4*)(src + h);
    float4 ww = *(const float4*)(wv + h);
    dot += e.x * ww.x + e.y * ww.y + e.z * ww.z + e.w * ww.w;
  }
#pragma unroll
  for (int off = 32; off; off >>= 1) dot += __shfl_xor(dot, off);
  if (lane == 0) *dst = dot;
}

// ---------------- cast: f32 [R][512] -> bf16 normal (opt. scaled by wsc) + bf16 transposed ----------------
template <int R>
__global__ __launch_bounds__(256) void cast_kernel(
    const float* __restrict__ src, const float* __restrict__ wsc,
    unsigned short* __restrict__ dstN, unsigned short* __restrict__ dstT) {
  int b = blockIdx.z;
  int p0 = blockIdx.y * 64, h0 = blockIdx.x * 64;
  src += (long)b * R * HDIM;
  dstN += (long)b * R * HDIM;
  dstT += (long)b * HDIM * R;
  __shared__ float T[64][65];
  int t = threadIdx.x;
  int c4 = (t & 15) * 4, r = t >> 4;
#pragma unroll
  for (int i = 0; i < 4; i++) {
    int row = r + 16 * i;
    float4 v = *(const float4*)(src + (long)(p0 + row) * HDIM + h0 + c4);
    T[row][c4] = v.x; T[row][c4 + 1] = v.y; T[row][c4 + 2] = v.z; T[row][c4 + 3] = v.w;
    float4 s = v;
    if (wsc) {
      s.x *= wsc[h0 + c4]; s.y *= wsc[h0 + c4 + 1];
      s.z *= wsc[h0 + c4 + 2]; s.w *= wsc[h0 + c4 + 3];
    }
    ushort4v o = {f2bf(s.x), f2bf(s.y), f2bf(s.z), f2bf(s.w)};
    *(ushort4v*)(dstN + (long)(p0 + row) * HDIM + h0 + c4) = o;
  }
  __syncthreads();
#pragma unroll
  for (int i = 0; i < 4; i++) {
    int hh = r + 16 * i;  // local h index
    ushort4v o = {f2bf(T[c4 + 0][hh]), f2bf(T[c4 + 1][hh]),
                  f2bf(T[c4 + 2][hh]), f2bf(T[c4 + 3][hh])};
    *(ushort4v*)(dstT + (long)(h0 + hh) * R + p0 + c4) = o;
  }
}

// ---------------- MFMA NT GEMM: A [M][K] bf16, B [N][K] bf16, both lda=ldb=K ----------------
// EPI=0: U epilogue (bias+mask -> f32 Um [M][N] and UmT [N][M])
// EPI=1: out chunks {0:E, 1:v, 3:E*v} * mask  + dual bf16 Tout [N][M]
// EPI=2: out chunks {2:v, 4:E*v} * mask
template <int EPI>
__global__ __launch_bounds__(256) void mfma_gemm(
    const unsigned short* __restrict__ Ab, const unsigned short* __restrict__ Bb,
    int M, int N, int K,
    float* __restrict__ Um, float* __restrict__ UmT,
    const float* __restrict__ biasM, const float* __restrict__ biasN,
    const int* __restrict__ maskM, const int* __restrict__ maskN,
    float* __restrict__ outBase, const float* __restrict__ Esrc,
    unsigned short* __restrict__ Tout) {
  const int b = blockIdx.z;
  const unsigned short* A = Ab + (long)b * M * K;
  const unsigned short* B = Bb + (long)b * N * K;
  const int m0 = blockIdx.y * 128, n0 = blockIdx.x * 128;
  __shared__ unsigned short As[8192];  // [128 rows][64 k] bf16, XOR-swizzled
  __shared__ unsigned short Bs[8192];
  const int t = threadIdx.x, lane = t & 63, wid = t >> 6;
  const int wr = (wid >> 1) * 64, wc = (wid & 1) * 64;
  const int fr = lane & 15, fq = lane >> 4;
  f32x4 acc[4][4] = {};
  for (int k0 = 0; k0 < K; k0 += 64) {
    // ---- stage (reg -> LDS, swizzle on write) ----
#pragma unroll
    for (int i = 0; i < 4; i++) {
      int o = (t + i * 256) * 16;          // byte offset in 16KB tile
      int row = o >> 7;                    // 128B per row
      int col = (o & 127) >> 1;            // k element
      int swz = o ^ ((row & 7) << 4);
      short8 av = *(const short8*)(A + (long)(m0 + row) * K + k0 + col);
      *(short8*)((char*)As + swz) = av;
      short8 bv = *(const short8*)(B + (long)(n0 + row) * K + k0 + col);
      *(short8*)((char*)Bs + swz) = bv;
    }
    __syncthreads();
#pragma unroll
    for (int ks = 0; ks < 2; ks++) {
      short8 af[4], bfr[4];
#pragma unroll
      for (int i = 0; i < 4; i++) {
        int rowA = wr + i * 16 + fr;
        int aA = ((rowA << 7) + ks * 64 + fq * 16) ^ ((rowA & 7) << 4);
        af[i] = *(const short8*)((const char*)As + aA);
        int rowB = wc + i * 16 + fr;
        int aB = ((rowB << 7) + ks * 64 + fq * 16) ^ ((rowB & 7) << 4);
        bfr[i] = *(const short8*)((const char*)Bs + aB);
      }
#pragma unroll
      for (int i = 0; i < 4; i++)
#pragma unroll
        for (int j = 0; j < 4; j++)
          acc[i][j] = __builtin_amdgcn_mfma_f32_16x16x32_bf16(af[i], bfr[j], acc[i][j], 0, 0, 0);
    }
    __syncthreads();
  }
  // ---- epilogues ----
  if (EPI == 0) {
    const float* bM = biasM + (long)b * M;
    const float* bN = biasN + (long)b * N;
    const int* mM = maskM + (long)b * M;
    const int* mN = maskN + (long)b * N;
    float* UmB = Um + (long)b * M * N;
    float* UmTB = UmT + (long)b * M * N;
#pragma unroll
    for (int i = 0; i < 4; i++) {
#pragma unroll
      for (int j = 0; j < 4; j++) {
        int col = n0 + wc + j * 16 + fr;
        float bn = bN[col];
        int mn = mN[col];
        float4 tv;
#pragma unroll
        for (int r = 0; r < 4; r++) {
          int row = m0 + wr + i * 16 + fq * 4 + r;
          float v = acc[i][j][r] + bM[row] + bn;
          v = (mM[row] && mn) ? v : NEG_MAX;
          UmB[(long)row * N + col] = v;
          ((float*)&tv)[r] = v;
        }
        int row0 = m0 + wr + i * 16 + fq * 4;
        *(float4*)(UmTB + (long)col * M + row0) = tv;
      }
    }
  } else {
    float* outB = outBase + (long)b * M * GDIM;
    const float* EB = Esrc + (long)b * M * HDIM;
    unsigned short* ToutB = (EPI == 1) ? Tout + (long)b * N * M : nullptr;
#pragma unroll
    for (int i = 0; i < 4; i++) {
#pragma unroll
      for (int r = 0; r < 4; r++) {
        int row = m0 + wr + i * 16 + fq * 4 + r;
        float mm = (float)maskM[(long)b * M + row];
        float* orow = outB + (long)row * GDIM;
        const float* erow = EB + (long)row * HDIM;
#pragma unroll
        for (int j = 0; j < 4; j++) {
          int col = n0 + wc + j * 16 + fr;
          float v = acc[i][j][r];
          float e = erow[col];
          if (EPI == 1) {
            orow[col] = e * mm;
            orow[HDIM + col] = v * mm;
            orow[3 * HDIM + col] = e * v * mm;
          } else {
            orow[2 * HDIM + col] = v * mm;
            orow[4 * HDIM + col] = e * v * mm;
          }
        }
      }
      if (EPI == 1) {
#pragma unroll
        for (int j = 0; j < 4; j++) {
          int col = n0 + wc + j * 16 + fr;
          int row0 = m0 + wr + i * 16 + fq * 4;
          ushort4v o = {f2bf(acc[i][j][0]), f2bf(acc[i][j][1]),
                        f2bf(acc[i][j][2]), f2bf(acc[i][j][3])};
          *(ushort4v*)(ToutB + (long)col * M + row0) = o;
        }
      }
    }
  }
}

// ---------------- row softmax over q (len 128), wave per row -> Ap bf16 ----------------
__global__ __launch_bounds__(256) void rowsoftmax_kernel(
    const float* __restrict__ Um, unsigned short* __restrict__ Ap,
    const int* __restrict__ mp, const int* __restrict__ mq) {
  int wid = blockIdx.x * 4 + (threadIdx.x >> 6);  // = b*LP + p
  int lane = threadIdx.x & 63;
  int b = wid >> 9;
  const float* row = Um + (long)wid * LQ;
  float v0 = row[lane], v1 = row[lane + 64];
  float m = fmaxf(v0, v1);
#pragma unroll
  for (int off = 32; off; off >>= 1) m = fmaxf(m, __shfl_xor(m, off));
  float e0 = __expf(v0 - m), e1 = __expf(v1 - m);
  float s = e0 + e1;
#pragma unroll
  for (int off = 32; off; off >>= 1) s += __shfl_xor(s, off);
  float inv = s > 0.f ? 1.f / s : 0.f;
  int mpv = mp[wid];
  bool ok0 = mpv && mq[b * LQ + lane];
  bool ok1 = mpv && mq[b * LQ + lane + 64];
  Ap[(long)wid * LQ + lane] = ok0 ? f2bf(e0 * inv) : 0;
  Ap[(long)wid * LQ + lane + 64] = ok1 ? f2bf(e1 * inv) : 0;
}

// ---------------- col softmax over p (len 512) on UmT rows, wave per row -> BpT bf16 ----------------
__global__ __launch_bounds__(256) void colsoftmaxT_kernel(
    const float* __restrict__ UmT, unsigned short* __restrict__ BpT,
    const int* __restrict__ mp, const int* __restrict__ mq) {
  int wid = blockIdx.x * 4 + (threadIdx.x >> 6);  // = b*LQ + q
  int lane = threadIdx.x & 63;
  int b = wid >> 7;
  const float* row = UmT + (long)wid * LP;
  float v[8];
  float m = NEG_MAX;
#pragma unroll
  for (int i = 0; i < 8; i++) { v[i] = row[lane + 64 * i]; m = fmaxf(m, v[i]); }
#pragma unroll
  for (int off = 32; off; off >>= 1) m = fmaxf(m, __shfl_xor(m, off));
  float e[8];
  float s = 0.f;
#pragma unroll
  for (int i = 0; i < 8; i++) { e[i] = __expf(v[i] - m); s += e[i]; }
#pragma unroll
  for (int off = 32; off; off >>= 1) s += __shfl_xor(s, off);
  float inv = s > 0.f ? 1.f / s : 0.f;
  int mqv = mq[wid];
#pragma unroll
  for (int i = 0; i < 8; i++) {
    int p = lane + 64 * i;
    bool ok = mqv && mp[b * LP + p];
    BpT[(long)wid * LP + p] = ok ? f2bf(e[i] * inv) : 0;
  }
}

extern "C" void kernel_launch(void* const* d_in, const int* in_sizes, int n_in,
                              void* d_out, int out_size, void* d_ws, size_t ws_size,
                              hipStream_t stream) {
  const float* Eq = (const float*)d_in[0];   // (32,128,512)
  const float* Ep = (const float*)d_in[1];   // (32,512,512)
  const int* mq = (const int*)d_in[2];       // (32,128)
  const int* mp = (const int*)d_in[3];       // (32,512)
  const float* w = (const float*)d_in[4];    // (1536,)
  float* out = (float*)d_out;
  float* out_gpq = out;                                  // (32,128,2560)
  float* out_gqp = out + (long)BBATCH * LQ * GDIM;       // (32,512,2560)

  // ws layout (bf16 operand arrays + f32 U)
  unsigned short* Epw = (unsigned short*)d_ws;           // [32][512][512] bf16 (Ep * w_m)
  unsigned short* EpT = Epw + 32L * 512 * 512;           // [32][512h][512p]
  unsigned short* Eqb = EpT + 32L * 512 * 512;           // [32][128][512]
  unsigned short* EqT = Eqb + 32L * 128 * 512;           // [32][512h][128q]
  unsigned short* Apb = EqT + 32L * 512 * 128;           // [32][512p][128q]
  unsigned short* BpT = Apb + 32L * 512 * 128;           // [32][128q][512p]
  unsigned short* A1T = BpT + 32L * 128 * 512;           // [32][512h][512p]
  unsigned short* B1T = A1T + 32L * 512 * 512;           // [32][512h][128q]
  float* Um = (float*)(B1T + 32L * 512 * 128);           // [32][512p][128q]
  float* UmT = Um + 32L * 512 * 128;                     // [32][128q][512p]
  float* epb = UmT + 32L * 512 * 128;                    // [32][512]
  float* eqb2 = epb + 32L * 512;                         // [32][128]

  // 1. casts
  cast_kernel<512><<<dim3(8, 8, BBATCH), 256, 0, stream>>>(Ep, w + 2 * HDIM, Epw, EpT);
  cast_kernel<128><<<dim3(8, 2, BBATCH), 256, 0, stream>>>(Eq, nullptr, Eqb, EqT);

  // 2. bias vectors
  bias_kernel<<<(BBATCH * LP + BBATCH * LQ) / 4, 256, 0, stream>>>(Ep, Eq, w, epb, eqb2);

  // 3. U = (Ep.*wm) @ Eq^T + ep + eq, masked -> Um [p][q] + UmT [q][p]
  mfma_gemm<0><<<dim3(1, 4, BBATCH), 256, 0, stream>>>(
      Epw, Eqb, LP, LQ, HDIM, Um, UmT, epb, eqb2, mp, mq, nullptr, nullptr, nullptr);

  // 4. softmaxes
  rowsoftmax_kernel<<<BBATCH * LP / 4, 256, 0, stream>>>(Um, Apb, mp, mq);
  colsoftmaxT_kernel<<<BBATCH * LQ / 4, 256, 0, stream>>>(UmT, BpT, mp, mq);

  // 5. A1 = Ap @ Eq (M=512p, N=512h, K=128) -> gqp chunks {E,A1,E*A1} + A1T
  mfma_gemm<1><<<dim3(4, 4, BBATCH), 256, 0, stream>>>(
      Apb, EqT, LP, HDIM, LQ, nullptr, nullptr, nullptr, nullptr, mp, nullptr,
      out_gqp, Ep, A1T);

  // 6. B1 = Bp^T @ Ep (M=128q, N=512h, K=512) -> gpq chunks {E,B1,E*B1} + B1T
  mfma_gemm<1><<<dim3(4, 1, BBATCH), 256, 0, stream>>>(
      BpT, EpT, LQ, HDIM, LP, nullptr, nullptr, nullptr, nullptr, mq, nullptr,
      out_gpq, Eq, B1T);

  // 7. A2 = Ap @ B1 (M=512p, N=512h, K=128) -> gqp chunks {A2, E*A2}
  mfma_gemm<2><<<dim3(4, 4, BBATCH), 256, 0, stream>>>(
      Apb, B1T, LP, HDIM, LQ, nullptr, nullptr, nullptr, nullptr, mp, nullptr,
      out_gqp, Ep, nullptr);

  // 8. B2 = Bp^T @ A1 (M=128q, N=512h, K=512) -> gpq chunks {B2, E*B2}
  mfma_gemm<2><<<dim3(4, 1, BBATCH), 256, 0, stream>>>(
      BpT, A1T, LQ, HDIM, LP, nullptr, nullptr, nullptr, nullptr, mq, nullptr,
      out_gpq, Eq, nullptr);
}